// Round 3
// baseline (219.874 us; speedup 1.0000x reference)
//
#include <hip/hip_runtime.h>
#include <math.h>

#define EPS 1e-12f

typedef unsigned short ushort_t;
typedef __attribute__((ext_vector_type(8))) short short8;
typedef __attribute__((ext_vector_type(4))) float f32x4;
typedef __attribute__((ext_vector_type(4))) unsigned short ushort4v;
typedef __attribute__((ext_vector_type(2))) unsigned int uint2v;

// ---- workspace layout (float units) ----
#define WS_WB_F 0
#define WS_WO_F 24576
#define WS_TH_F 40960
#define WS_PH_F 1089536
#define WS_G_F  1351680

__device__ __forceinline__ ushort_t f2bf(float f) {
  unsigned int u = __float_as_uint(f);
  u += 0x7fffu + ((u >> 16) & 1u);
  return (ushort_t)(u >> 16);
}
__device__ __forceinline__ float bf2f(ushort_t u) {
  return __uint_as_float(((unsigned int)u) << 16);
}
__device__ __forceinline__ unsigned int pack_bf2(float lo, float hi) {
  return (unsigned int)f2bf(lo) | ((unsigned int)f2bf(hi) << 16);
}

// async 16B global->LDS DMA (linear LDS dest = wave base + lane*16)
__device__ __forceinline__ void gload_lds16(const ushort_t* g, ushort_t* l) {
  __builtin_amdgcn_global_load_lds(
      (const __attribute__((address_space(1))) unsigned int*)g,
      (__attribute__((address_space(3))) unsigned int*)l, 16, 0, 0);
}

__device__ __forceinline__ float block_reduce_sum(float v, float* red) {
  int t = threadIdx.x;
  red[t] = v;
  __syncthreads();
  #pragma unroll
  for (int s = 128; s > 0; s >>= 1) {
    if (t < s) red[t] += red[t + s];
    __syncthreads();
  }
  float r = red[0];
  __syncthreads();
  return r;
}

// One block per weight: spectral-norm scale, emit bf16 weights in
// MFMA-fragment order (coalesced consumer loads).
__global__ __launch_bounds__(256) void sn_kernel(
    const float* __restrict__ Wt, const float* __restrict__ Wp,
    const float* __restrict__ Wg, const float* __restrict__ Wo,
    const float* __restrict__ ut, const float* __restrict__ up,
    const float* __restrict__ ug, const float* __restrict__ uo,
    float* __restrict__ ws) {
  __shared__ float red[256];
  __shared__ float ub[256];
  __shared__ float vb[256];
  const float* W; const float* u; int O, Ci;
  switch (blockIdx.x) {
    case 0:  W = Wt; u = ut; O = 32;  Ci = 256; break;
    case 1:  W = Wp; u = up; O = 32;  Ci = 256; break;
    case 2:  W = Wg; u = ug; O = 128; Ci = 256; break;
    default: W = Wo; u = uo; O = 256; Ci = 128; break;
  }
  int t = threadIdx.x;
  if (t < O) ub[t] = u[t];
  __syncthreads();
  float tv = 0.f;
  if (t < Ci) {
    for (int o = 0; o < O; o++) tv += W[o * Ci + t] * ub[o];
  }
  float nt2 = block_reduce_sum((t < Ci) ? tv * tv : 0.f, red);
  float ntn = sqrtf(nt2);
  if (t < Ci) vb[t] = tv / (ntn + EPS);
  __syncthreads();
  float sv = 0.f;
  if (t < O) {
    const float* Wr = W + (size_t)t * Ci;
    for (int c = 0; c < Ci; c += 4) {
      float4 wv = *(const float4*)(Wr + c);
      sv += wv.x * vb[c] + wv.y * vb[c + 1] + wv.z * vb[c + 2] + wv.w * vb[c + 3];
    }
  }
  float ss = block_reduce_sum((t < O) ? sv * sv : 0.f, red);
  float ns = sqrtf(ss);
  float sigma = ss / (ns + EPS);
  float inv = 1.f / sigma;
  int total = O * Ci;
  if (blockIdx.x == 3) {
    // Wo fragment order: [(kc*16+oct)*64 + quad*16 + l16]*8 + j
    ushort_t* dst = (ushort_t*)(ws + WS_WO_F);
    for (int i = t; i < total; i += 256) {
      int o = i >> 7, c = i & 127;
      int oct = o >> 4, l16o = o & 15, kc = c >> 5, qd = (c >> 3) & 3, j = c & 7;
      dst[(((kc * 16 + oct) * 64 + qd * 16 + l16o) << 3) + j] = f2bf(W[i] * inv);
    }
  } else {
    // proj fragment order: [(mtg*8+kc)*64 + quad*16 + l16]*8 + j  (mtg global 0..11)
    int base_row = (blockIdx.x == 0) ? 0 : (blockIdx.x == 1 ? 32 : 64);
    ushort_t* dst = (ushort_t*)(ws + WS_WB_F);
    for (int i = t; i < total; i += 256) {
      int o = i >> 8, c = i & 255;
      int og = base_row + o;
      int mtg = og >> 4, l16o = og & 15, kc = c >> 5, qd = (c >> 3) & 3, j = c & 7;
      dst[(((mtg * 8 + kc) * 64 + qd * 16 + l16o) << 3) + j] = f2bf(W[i] * inv);
    }
  }
}

// Fused projection GEMM; weights read in fragment order (coalesced).
__global__ __launch_bounds__(256, 2) void proj_mfma(
    const float* __restrict__ x, const ushort_t* __restrict__ wb,
    ushort_t* __restrict__ theta_b, ushort_t* __restrict__ phi_b,
    ushort_t* __restrict__ g_b) {
  __shared__ ushort_t xb[128 * 264];
  const int t = threadIdx.x;
  const int n = blockIdx.y;
  const int l0 = blockIdx.x * 128;
  const float* xn = x + ((size_t)n * 256) * 4096 + l0;
  {
    const int lrel = t & 127;
    const int half = t >> 7;
    #pragma unroll 4
    for (int ch = 0; ch < 16; ++ch) {
      int chunk = half * 16 + ch;
      short8 v;
      #pragma unroll
      for (int j = 0; j < 8; ++j) {
        float f = xn[(size_t)(chunk * 8 + j) * 4096 + lrel];
        v[j] = (short)f2bf(f);
      }
      *(short8*)(&xb[lrel * 264 + chunk * 8]) = v;
    }
  }
  __syncthreads();
  const int w = t >> 6;
  const int lane = t & 63;
  const int quad = lane >> 4;
  const int l16 = lane & 15;
  const int rowA = (w * 16 + l16) * 264;
  const int rowB = (64 + w * 16 + l16) * 264;
  const int hd = blockIdx.x;
  #pragma unroll 1
  for (int pass = 0; pass < 2; ++pass) {
    f32x4 accA[6], accB[6];
    #pragma unroll
    for (int i = 0; i < 6; ++i) {
      accA[i] = (f32x4){0.f, 0.f, 0.f, 0.f};
      accB[i] = (f32x4){0.f, 0.f, 0.f, 0.f};
    }
    #pragma unroll
    for (int kc = 0; kc < 8; ++kc) {
      short8 bA = *(const short8*)(&xb[rowA + kc * 32 + quad * 8]);
      short8 bB = *(const short8*)(&xb[rowB + kc * 32 + quad * 8]);
      #pragma unroll
      for (int mt = 0; mt < 6; ++mt) {
        int mtg = pass * 6 + mt;
        short8 aW = *(const short8*)(wb + (((size_t)(mtg * 8 + kc) * 64 + lane) << 3));
        accA[mt] = __builtin_amdgcn_mfma_f32_16x16x32_bf16(aW, bA, accA[mt], 0, 0, 0);
        accB[mt] = __builtin_amdgcn_mfma_f32_16x16x32_bf16(aW, bB, accB[mt], 0, 0, 0);
      }
    }
    #pragma unroll
    for (int mt = 0; mt < 6; ++mt) {
      int mtg = pass * 6 + mt;
      if (mtg < 2) {
        int lA = l0 + w * 16 + l16;
        ushort4v vA, vB;
        #pragma unroll
        for (int r = 0; r < 4; ++r) { vA[r] = f2bf(accA[mt][r]); vB[r] = f2bf(accB[mt][r]); }
        *(ushort4v*)(theta_b + ((size_t)n * 4096 + lA) * 32 + mtg * 16 + quad * 4) = vA;
        *(ushort4v*)(theta_b + ((size_t)n * 4096 + lA + 64) * 32 + mtg * 16 + quad * 4) = vB;
      } else {
        float pm[4];
        #pragma unroll
        for (int r = 0; r < 4; ++r) {
          float v = fmaxf(accA[mt][r], accB[mt][r]);
          v = fmaxf(v, __shfl_xor(v, 1));
          pm[r] = v;
        }
        if ((l16 & 1) == 0) {
          int m = hd * 32 + w * 8 + (l16 >> 1);
          if (mtg < 4) {
            ushort4v vv;
            #pragma unroll
            for (int r = 0; r < 4; ++r) vv[r] = f2bf(pm[r]);
            *(ushort4v*)(phi_b + ((size_t)n * 1024 + m) * 32 + (mtg - 2) * 16 + quad * 4) = vv;
          } else {
            int cg0 = (mtg - 4) * 16 + quad * 4;
            #pragma unroll
            for (int r = 0; r < 4; ++r)
              g_b[((size_t)n * 128 + cg0 + r) * 1024 + m] = f2bf(pm[r]);
          }
        }
      }
    }
  }
}

// g staged per wave: 8 fragment-linear 1KB blocks (j,s); conflict-free reads.
__device__ __forceinline__ void stage_g(const ushort_t* gN, ushort_t* buf,
                                        int m0, int w, int l16, int quad) {
  #pragma unroll
  for (int b = 0; b < 8; ++b) {
    int idx = w * 8 + b;
    int j = idx >> 2, s = idx & 3;
    const ushort_t* src = gN + (size_t)(j * 16 + l16) * 1024 + m0 + s * 32 + quad * 8;
    gload_lds16(src, buf + (j * 4 + s) * 512);
  }
}

__device__ __forceinline__ void softmax_step(f32x4* st, float& M, float& L,
                                             f32x4* oa, unsigned int* pk) {
  f32x4 m4 = st[0];
  #pragma unroll
  for (int i = 1; i < 8; ++i) {
    #pragma unroll
    for (int r = 0; r < 4; ++r) m4[r] = fmaxf(m4[r], st[i][r]);
  }
  float mx = fmaxf(fmaxf(m4[0], m4[1]), fmaxf(m4[2], m4[3]));
  mx = fmaxf(mx, __shfl_xor(mx, 16));
  mx = fmaxf(mx, __shfl_xor(mx, 32));
  float nm = fmaxf(M, mx);
  float alpha = __expf(M - nm);
  M = nm;
  #pragma unroll
  for (int i = 0; i < 8; ++i) {
    #pragma unroll
    for (int r = 0; r < 4; ++r) st[i][r] = __expf(st[i][r] - nm);
  }
  f32x4 s4 = st[0];
  #pragma unroll
  for (int i = 1; i < 8; ++i) {
    #pragma unroll
    for (int r = 0; r < 4; ++r) s4[r] += st[i][r];
  }
  float ps = (s4[0] + s4[1]) + (s4[2] + s4[3]);
  ps += __shfl_xor(ps, 16);
  ps += __shfl_xor(ps, 32);
  L = L * alpha + ps;
  #pragma unroll
  for (int j = 0; j < 8; ++j) {
    #pragma unroll
    for (int r = 0; r < 4; ++r) oa[j][r] *= alpha;
  }
  #pragma unroll
  for (int i = 0; i < 8; ++i) {
    pk[2 * i]     = pack_bf2(st[i][0], st[i][1]);
    pk[2 * i + 1] = pack_bf2(st[i][2], st[i][3]);
  }
}

// Flash attention v4: 32 q/wave (2 q-groups, 2x g/phi fragment reuse),
// fragment-linear double-buffered g LDS (conflict-free ds_read_b128,
// one barrier per iter), setprio around PV cluster.
__global__ __launch_bounds__(256, 2) void attn_mfma(
    const float* __restrict__ x,
    const ushort_t* __restrict__ theta_b,
    const ushort_t* __restrict__ phi_b,
    const ushort_t* __restrict__ g_b,
    const ushort_t* __restrict__ Wo_fb,
    const float* __restrict__ gamma_p,
    float* __restrict__ out) {
  // [0, 32768)     : gbuf0 (32 fragment blocks x 1KB)
  // [32768, 65536) : gbuf1
  // [0, 67584)     : outb [256 oc][132 l] bf16 (epilogue overlay)
  // [67584, 77824) : pstage, per wave 2 qg x 320 uints
  __shared__ __align__(16) unsigned char smem[77824];
  ushort_t* gbuf0 = (ushort_t*)smem;
  ushort_t* gbuf1 = (ushort_t*)(smem + 32768);
  ushort_t* outb  = (ushort_t*)smem;

  const int t = threadIdx.x;
  const int w = t >> 6;
  const int lane = t & 63;
  const int quad = lane >> 4;
  const int l16 = lane & 15;
  unsigned int* pw0 = (unsigned int*)(smem + 67584) + w * 640;
  unsigned int* pw1 = pw0 + 320;

  // XCD swizzle: grid 512, 64 blocks per XCD -> 2 images per XCD L2.
  const int flat = blockIdx.y * 32 + blockIdx.x;
  const int nf = ((flat & 7) << 6) | (flat >> 3);
  const int n = nf >> 5;
  const int l0 = (nf & 31) << 7;
  const int lqw = l0 + w * 32;

  const short8 bth0 = *(const short8*)(theta_b + ((size_t)n * 4096 + lqw + l16) * 32 + quad * 8);
  const short8 bth1 = *(const short8*)(theta_b + ((size_t)n * 4096 + lqw + 16 + l16) * 32 + quad * 8);
  const ushort_t* phiN = phi_b + (size_t)n * 1024 * 32;
  const ushort_t* gN   = g_b + (size_t)n * 128 * 1024;

  f32x4 oacc0[8], oacc1[8];
  #pragma unroll
  for (int j = 0; j < 8; ++j) {
    oacc0[j] = (f32x4){0.f, 0.f, 0.f, 0.f};
    oacc1[j] = (f32x4){0.f, 0.f, 0.f, 0.f};
  }
  float M0 = -3.0e38f, L0v = 0.f, M1 = -3.0e38f, L1v = 0.f;

  stage_g(gN, gbuf0, 0, w, l16, quad);   // prologue

  #pragma unroll 1
  for (int mc = 0; mc < 8; ++mc) {
    const int m0 = mc * 128;
    ushort_t* cbuf = (mc & 1) ? gbuf1 : gbuf0;
    ushort_t* nbuf = (mc & 1) ? gbuf0 : gbuf1;
    // ---- QK^T for both q-groups (phi frags loaded once) ----
    short8 aph[8];
    #pragma unroll
    for (int i = 0; i < 8; ++i)
      aph[i] = *(const short8*)(phiN + (size_t)(m0 + i * 16 + l16) * 32 + quad * 8);
    const f32x4 z = (f32x4){0.f, 0.f, 0.f, 0.f};
    f32x4 st0[8], st1[8];
    #pragma unroll
    for (int i = 0; i < 8; ++i) {
      st0[i] = __builtin_amdgcn_mfma_f32_16x16x32_bf16(aph[i], bth0, z, 0, 0, 0);
      st1[i] = __builtin_amdgcn_mfma_f32_16x16x32_bf16(aph[i], bth1, z, 0, 0, 0);
    }
    // ---- two independent lane-local softmax chains ----
    unsigned int pk0[16], pk1[16];
    softmax_step(st0, M0, L0v, oacc0, pk0);
    softmax_step(st1, M1, L1v, oacc1, pk1);
    __syncthreads();                     // publish cbuf (drains DMA)
    if (mc < 7) stage_g(gN, nbuf, m0 + 128, w, l16, quad);  // hide under PV+next QK
    // ---- PV: each gf fragment feeds both q-groups ----
    __builtin_amdgcn_s_setprio(1);
    #pragma unroll
    for (int s = 0; s < 4; ++s) {
      *(uint2v*)&pw0[l16 * 20 + quad * 2]     = (uint2v){pk0[4 * s],     pk0[4 * s + 1]};
      *(uint2v*)&pw0[l16 * 20 + 8 + quad * 2] = (uint2v){pk0[4 * s + 2], pk0[4 * s + 3]};
      *(uint2v*)&pw1[l16 * 20 + quad * 2]     = (uint2v){pk1[4 * s],     pk1[4 * s + 1]};
      *(uint2v*)&pw1[l16 * 20 + 8 + quad * 2] = (uint2v){pk1[4 * s + 2], pk1[4 * s + 3]};
      short8 pb0 = *(const short8*)&pw0[l16 * 20 + quad * 4];
      short8 pb1 = *(const short8*)&pw1[l16 * 20 + quad * 4];
      #pragma unroll
      for (int j = 0; j < 8; ++j) {
        short8 gf = *(const short8*)(cbuf + (size_t)(j * 4 + s) * 512 + lane * 8);
        oacc0[j] = __builtin_amdgcn_mfma_f32_16x16x32_bf16(gf, pb0, oacc0[j], 0, 0, 0);
        oacc1[j] = __builtin_amdgcn_mfma_f32_16x16x32_bf16(gf, pb1, oacc1[j], 0, 0, 0);
      }
    }
    __builtin_amdgcn_s_setprio(0);
  }
  __syncthreads();   // all PV done; gbuf region becomes outb

  // ---- epilogue: D2[q][oc] = (O[q][cg]/L[q]) . Wo[oc][cg], per q-group ----
  #pragma unroll
  for (int qg = 0; qg < 2; ++qg) {
    f32x4* oa = qg ? oacc1 : oacc0;
    unsigned int* pwq = qg ? pw1 : pw0;
    const float invL = 1.f / (qg ? L1v : L0v);
    f32x4 acc2[16];
    #pragma unroll
    for (int i = 0; i < 16; ++i) acc2[i] = (f32x4){0.f, 0.f, 0.f, 0.f};
    #pragma unroll
    for (int kc = 0; kc < 4; ++kc) {
      unsigned int e0 = pack_bf2(oa[2 * kc][0] * invL, oa[2 * kc][1] * invL);
      unsigned int e1 = pack_bf2(oa[2 * kc][2] * invL, oa[2 * kc][3] * invL);
      unsigned int e2 = pack_bf2(oa[2 * kc + 1][0] * invL, oa[2 * kc + 1][1] * invL);
      unsigned int e3 = pack_bf2(oa[2 * kc + 1][2] * invL, oa[2 * kc + 1][3] * invL);
      *(uint2v*)&pwq[l16 * 20 + quad * 2]     = (uint2v){e0, e1};
      *(uint2v*)&pwq[l16 * 20 + 8 + quad * 2] = (uint2v){e2, e3};
      short8 aO = *(const short8*)&pwq[l16 * 20 + quad * 4];
      #pragma unroll
      for (int oct = 0; oct < 16; ++oct) {
        short8 bw = *(const short8*)(Wo_fb + (((size_t)(kc * 16 + oct) * 64 + lane) << 3));
        acc2[oct] = __builtin_amdgcn_mfma_f32_16x16x32_bf16(aO, bw, acc2[oct], 0, 0, 0);
      }
    }
    #pragma unroll
    for (int oct = 0; oct < 16; ++oct) {
      #pragma unroll
      for (int r = 0; r < 4; ++r)
        outb[(oct * 16 + l16) * 132 + w * 32 + qg * 16 + quad * 4 + r] = f2bf(acc2[oct][r]);
    }
  }
  __syncthreads();
  // ---- residual + coalesced stores (128 cols) ----
  {
    const float gm = gamma_p[0];
    const int lid = t & 31;
    const int ocr = t >> 5;
    #pragma unroll 8
    for (int ocg = 0; ocg < 32; ++ocg) {
      int row = ocg * 8 + ocr;
      ushort4v ov = *(const ushort4v*)(&outb[row * 132 + lid * 4]);
      const float* xp = x + ((size_t)n * 256 + row) * 4096 + l0 + lid * 4;
      float* op = out + ((size_t)n * 256 + row) * 4096 + l0 + lid * 4;
      float4 xv = *(const float4*)xp;
      float4 v;
      v.x = xv.x + gm * bf2f(ov[0]);
      v.y = xv.y + gm * bf2f(ov[1]);
      v.z = xv.z + gm * bf2f(ov[2]);
      v.w = xv.w + gm * bf2f(ov[3]);
      *(float4*)op = v;
    }
  }
}

extern "C" void kernel_launch(void* const* d_in, const int* in_sizes, int n_in,
                              void* d_out, int out_size, void* d_ws, size_t ws_size,
                              hipStream_t stream) {
  const float* x  = (const float*)d_in[0];
  const float* Wt = (const float*)d_in[1];
  const float* Wp = (const float*)d_in[2];
  const float* Wg = (const float*)d_in[3];
  const float* Wo = (const float*)d_in[4];
  const float* ut = (const float*)d_in[5];
  const float* up = (const float*)d_in[6];
  const float* ug = (const float*)d_in[7];
  const float* uo = (const float*)d_in[8];
  const float* gamma = (const float*)d_in[9];
  float* ws  = (float*)d_ws;
  float* out = (float*)d_out;

  ushort_t* wb      = (ushort_t*)(ws + WS_WB_F);
  ushort_t* Wo_b    = (ushort_t*)(ws + WS_WO_F);
  ushort_t* theta_b = (ushort_t*)(ws + WS_TH_F);
  ushort_t* phi_b   = (ushort_t*)(ws + WS_PH_F);
  ushort_t* g_b     = (ushort_t*)(ws + WS_G_F);

  sn_kernel<<<4, 256, 0, stream>>>(Wt, Wp, Wg, Wo, ut, up, ug, uo, ws);
  proj_mfma<<<dim3(32, 16), 256, 0, stream>>>(x, wb, theta_b, phi_b, g_b);
  attn_mfma<<<dim3(32, 16), 256, 0, stream>>>(x, theta_b, phi_b, g_b, Wo_b, gamma, out);
}

// Round 5
// 217.406 us; speedup vs baseline: 1.0114x; 1.0114x over previous
//
#include <hip/hip_runtime.h>
#include <math.h>

#define EPS 1e-12f

typedef unsigned short ushort_t;
typedef __attribute__((ext_vector_type(8))) short short8;
typedef __attribute__((ext_vector_type(4))) float f32x4;
typedef __attribute__((ext_vector_type(4))) unsigned short ushort4v;
typedef __attribute__((ext_vector_type(2))) unsigned int uint2v;
typedef __attribute__((ext_vector_type(4))) unsigned int uint32x4;

// ---- workspace layout (float units) ----
#define WS_WB_F 0
#define WS_WO_F 24576
#define WS_TH_F 40960
#define WS_PH_F 1089536
#define WS_G_F  1351680

__device__ __forceinline__ ushort_t f2bf(float f) {
  unsigned int u = __float_as_uint(f);
  u += 0x7fffu + ((u >> 16) & 1u);
  return (ushort_t)(u >> 16);
}
__device__ __forceinline__ float bf2f(ushort_t u) {
  return __uint_as_float(((unsigned int)u) << 16);
}
__device__ __forceinline__ unsigned int pack_bf2(float lo, float hi) {
  return (unsigned int)f2bf(lo) | ((unsigned int)f2bf(hi) << 16);
}

// async 16B global->LDS DMA (linear LDS dest = wave base + lane*16)
__device__ __forceinline__ void gload_lds16(const ushort_t* g, ushort_t* l) {
  __builtin_amdgcn_global_load_lds(
      (const __attribute__((address_space(1))) unsigned int*)g,
      (__attribute__((address_space(3))) unsigned int*)l, 16, 0, 0);
}

__device__ __forceinline__ float block_reduce_sum(float v, float* red) {
  int t = threadIdx.x;
  red[t] = v;
  __syncthreads();
  #pragma unroll
  for (int s = 128; s > 0; s >>= 1) {
    if (t < s) red[t] += red[t + s];
    __syncthreads();
  }
  float r = red[0];
  __syncthreads();
  return r;
}

// One block per weight: spectral-norm scale, emit bf16 weights in
// MFMA-fragment order. Wo k-axis stored pi-permuted (kap = pi^-1) so the
// attn epilogue A-fragment comes straight from the PV accumulator.
__global__ __launch_bounds__(256) void sn_kernel(
    const float* __restrict__ Wt, const float* __restrict__ Wp,
    const float* __restrict__ Wg, const float* __restrict__ Wo,
    const float* __restrict__ ut, const float* __restrict__ up,
    const float* __restrict__ ug, const float* __restrict__ uo,
    float* __restrict__ ws) {
  __shared__ float red[256];
  __shared__ float ub[256];
  __shared__ float vb[256];
  const float* W; const float* u; int O, Ci;
  switch (blockIdx.x) {
    case 0:  W = Wt; u = ut; O = 32;  Ci = 256; break;
    case 1:  W = Wp; u = up; O = 32;  Ci = 256; break;
    case 2:  W = Wg; u = ug; O = 128; Ci = 256; break;
    default: W = Wo; u = uo; O = 256; Ci = 128; break;
  }
  int t = threadIdx.x;
  if (t < O) ub[t] = u[t];
  __syncthreads();
  float tv = 0.f;
  if (t < Ci) {
    for (int o = 0; o < O; o++) tv += W[o * Ci + t] * ub[o];
  }
  float nt2 = block_reduce_sum((t < Ci) ? tv * tv : 0.f, red);
  float ntn = sqrtf(nt2);
  if (t < Ci) vb[t] = tv / (ntn + EPS);
  __syncthreads();
  float sv = 0.f;
  if (t < O) {
    const float* Wr = W + (size_t)t * Ci;
    for (int c = 0; c < Ci; c += 4) {
      float4 wv = *(const float4*)(Wr + c);
      sv += wv.x * vb[c] + wv.y * vb[c + 1] + wv.z * vb[c + 2] + wv.w * vb[c + 3];
    }
  }
  float ss = block_reduce_sum((t < O) ? sv * sv : 0.f, red);
  float ns = sqrtf(ss);
  float sigma = ss / (ns + EPS);
  float inv = 1.f / sigma;
  int total = O * Ci;
  if (blockIdx.x == 3) {
    // Wo fragment order, k-axis pi^-1-permuted within each 32-chunk:
    // position kap holds source column cl, kap = pi^-1(cl).
    ushort_t* dst = (ushort_t*)(ws + WS_WO_F);
    for (int i = t; i < total; i += 256) {
      int o = i >> 7, c = i & 127;
      int oct = o >> 4, l16o = o & 15, kc = c >> 5, cl = c & 31;
      int kap = (cl < 16) ? ((cl >> 2) * 8 + (cl & 3))
                          : (((cl >> 2) & 3) * 8 + 4 + (cl & 3));
      dst[(((kc * 16 + oct) * 64 + (kap >> 3) * 16 + l16o) << 3) + (kap & 7)] =
          f2bf(W[i] * inv);
    }
  } else {
    // proj fragment order: [(mtg*8+kc)*64 + quad*16 + l16]*8 + j
    int base_row = (blockIdx.x == 0) ? 0 : (blockIdx.x == 1 ? 32 : 64);
    ushort_t* dst = (ushort_t*)(ws + WS_WB_F);
    for (int i = t; i < total; i += 256) {
      int o = i >> 8, c = i & 255;
      int og = base_row + o;
      int mtg = og >> 4, l16o = og & 15, kc = c >> 5, qd = (c >> 3) & 3, j = c & 7;
      dst[(((mtg * 8 + kc) * 64 + qd * 16 + l16o) << 3) + j] = f2bf(W[i] * inv);
    }
  }
}

// Fused projection GEMM. phi rows stored pi-permuted within each 32-key
// chunk (stored[pi(kg)] = phi[kg]) so attn's QK C-layout registers ARE the
// PV B-fragment; g stays logical.
__global__ __launch_bounds__(256, 2) void proj_mfma(
    const float* __restrict__ x, const ushort_t* __restrict__ wb,
    ushort_t* __restrict__ theta_b, ushort_t* __restrict__ phi_b,
    ushort_t* __restrict__ g_b) {
  __shared__ ushort_t xb[128 * 264];
  const int t = threadIdx.x;
  const int n = blockIdx.y;
  const int l0 = blockIdx.x * 128;
  const float* xn = x + ((size_t)n * 256) * 4096 + l0;
  {
    const int lrel = t & 127;
    const int half = t >> 7;
    #pragma unroll 4
    for (int ch = 0; ch < 16; ++ch) {
      int chunk = half * 16 + ch;
      short8 v;
      #pragma unroll
      for (int j = 0; j < 8; ++j) {
        float f = xn[(size_t)(chunk * 8 + j) * 4096 + lrel];
        v[j] = (short)f2bf(f);
      }
      *(short8*)(&xb[lrel * 264 + chunk * 8]) = v;
    }
  }
  __syncthreads();
  const int w = t >> 6;
  const int lane = t & 63;
  const int quad = lane >> 4;
  const int l16 = lane & 15;
  const int rowA = (w * 16 + l16) * 264;
  const int rowB = (64 + w * 16 + l16) * 264;
  const int hd = blockIdx.x;
  #pragma unroll 1
  for (int pass = 0; pass < 2; ++pass) {
    f32x4 accA[6], accB[6];
    #pragma unroll
    for (int i = 0; i < 6; ++i) {
      accA[i] = (f32x4){0.f, 0.f, 0.f, 0.f};
      accB[i] = (f32x4){0.f, 0.f, 0.f, 0.f};
    }
    #pragma unroll
    for (int kc = 0; kc < 8; ++kc) {
      short8 bA = *(const short8*)(&xb[rowA + kc * 32 + quad * 8]);
      short8 bB = *(const short8*)(&xb[rowB + kc * 32 + quad * 8]);
      #pragma unroll
      for (int mt = 0; mt < 6; ++mt) {
        int mtg = pass * 6 + mt;
        short8 aW = *(const short8*)(wb + (((size_t)(mtg * 8 + kc) * 64 + lane) << 3));
        accA[mt] = __builtin_amdgcn_mfma_f32_16x16x32_bf16(aW, bA, accA[mt], 0, 0, 0);
        accB[mt] = __builtin_amdgcn_mfma_f32_16x16x32_bf16(aW, bB, accB[mt], 0, 0, 0);
      }
    }
    #pragma unroll
    for (int mt = 0; mt < 6; ++mt) {
      int mtg = pass * 6 + mt;
      if (mtg < 2) {
        int lA = l0 + w * 16 + l16;
        ushort4v vA, vB;
        #pragma unroll
        for (int r = 0; r < 4; ++r) { vA[r] = f2bf(accA[mt][r]); vB[r] = f2bf(accB[mt][r]); }
        *(ushort4v*)(theta_b + ((size_t)n * 4096 + lA) * 32 + mtg * 16 + quad * 4) = vA;
        *(ushort4v*)(theta_b + ((size_t)n * 4096 + lA + 64) * 32 + mtg * 16 + quad * 4) = vB;
      } else {
        float pm[4];
        #pragma unroll
        for (int r = 0; r < 4; ++r) {
          float v = fmaxf(accA[mt][r], accB[mt][r]);
          v = fmaxf(v, __shfl_xor(v, 1));
          pm[r] = v;
        }
        if ((l16 & 1) == 0) {
          int rr = l16 >> 1;
          if (mtg < 4) {
            // pi-permuted phi row: kg = w*8+rr -> pi(kg)
            int mp = hd * 32 + ((rr & 4) ? 16 : 0) + w * 4 + (rr & 3);
            ushort4v vv;
            #pragma unroll
            for (int r = 0; r < 4; ++r) vv[r] = f2bf(pm[r]);
            *(ushort4v*)(phi_b + ((size_t)n * 1024 + mp) * 32 + (mtg - 2) * 16 + quad * 4) = vv;
          } else {
            int m = hd * 32 + w * 8 + rr;   // g stays logical
            int cg0 = (mtg - 4) * 16 + quad * 4;
            #pragma unroll
            for (int r = 0; r < 4; ++r)
              g_b[((size_t)n * 128 + cg0 + r) * 1024 + m] = f2bf(pm[r]);
          }
        }
      }
    }
  }
}

// g staged per wave: 8 fragment-linear 1KB blocks (j,s); conflict-free reads.
__device__ __forceinline__ void stage_g(const ushort_t* gN, ushort_t* buf,
                                        int m0, int w, int l16, int quad) {
  #pragma unroll
  for (int b = 0; b < 8; ++b) {
    int idx = w * 8 + b;
    int j = idx >> 2, s = idx & 3;
    gload_lds16(gN + (size_t)(j * 16 + l16) * 1024 + m0 + s * 32 + quad * 8,
                buf + (j * 4 + s) * 512);
  }
}

__device__ __forceinline__ void softmax_step(f32x4* st, float& M, float& L,
                                             f32x4* oa, unsigned int* pk) {
  f32x4 m4 = st[0];
  #pragma unroll
  for (int i = 1; i < 8; ++i) {
    #pragma unroll
    for (int r = 0; r < 4; ++r) m4[r] = fmaxf(m4[r], st[i][r]);
  }
  float mx = fmaxf(fmaxf(m4[0], m4[1]), fmaxf(m4[2], m4[3]));
  mx = fmaxf(mx, __shfl_xor(mx, 16));
  mx = fmaxf(mx, __shfl_xor(mx, 32));
  float nm = fmaxf(M, mx);
  float alpha = __expf(M - nm);
  M = nm;
  #pragma unroll
  for (int i = 0; i < 8; ++i) {
    #pragma unroll
    for (int r = 0; r < 4; ++r) st[i][r] = __expf(st[i][r] - nm);
  }
  f32x4 s4 = st[0];
  #pragma unroll
  for (int i = 1; i < 8; ++i) {
    #pragma unroll
    for (int r = 0; r < 4; ++r) s4[r] += st[i][r];
  }
  float ps = (s4[0] + s4[1]) + (s4[2] + s4[3]);
  ps += __shfl_xor(ps, 16);
  ps += __shfl_xor(ps, 32);
  L = L * alpha + ps;
  #pragma unroll
  for (int j = 0; j < 8; ++j) {
    #pragma unroll
    for (int r = 0; r < 4; ++r) oa[j][r] *= alpha;
  }
  #pragma unroll
  for (int i = 0; i < 8; ++i) {
    pk[2 * i]     = pack_bf2(st[i][0], st[i][1]);
    pk[2 * i + 1] = pack_bf2(st[i][2], st[i][3]);
  }
}

// Flash attention v6 (= R3 structure + pi-permutation): pb/aO come directly
// from the lane's own packed registers — no pstage LDS round-trips.
__global__ __launch_bounds__(256, 2) void attn_mfma(
    const float* __restrict__ x,
    const ushort_t* __restrict__ theta_b,
    const ushort_t* __restrict__ phi_b,
    const ushort_t* __restrict__ g_b,
    const ushort_t* __restrict__ Wo_fb,
    const float* __restrict__ gamma_p,
    float* __restrict__ out) {
  // [0,32768) gbuf0 | [32768,65536) gbuf1 | overlay: outb [256][132] = 67584
  __shared__ __align__(16) unsigned char smem[67584];
  ushort_t* gbuf0 = (ushort_t*)smem;
  ushort_t* gbuf1 = (ushort_t*)(smem + 32768);
  ushort_t* outb  = (ushort_t*)smem;

  const int t = threadIdx.x;
  const int w = t >> 6;
  const int lane = t & 63;
  const int quad = lane >> 4;
  const int l16 = lane & 15;

  // XCD swizzle: grid 512, 64 blocks per XCD -> 2 images per XCD L2.
  const int flat = blockIdx.y * 32 + blockIdx.x;
  const int nf = ((flat & 7) << 6) | (flat >> 3);
  const int n = nf >> 5;
  const int l0 = (nf & 31) << 7;
  const int lqw = l0 + w * 32;

  const short8 bth0 = *(const short8*)(theta_b + ((size_t)n * 4096 + lqw + l16) * 32 + quad * 8);
  const short8 bth1 = *(const short8*)(theta_b + ((size_t)n * 4096 + lqw + 16 + l16) * 32 + quad * 8);
  const ushort_t* phiN = phi_b + (size_t)n * 1024 * 32;
  const ushort_t* gN   = g_b + (size_t)n * 128 * 1024;

  f32x4 oacc0[8], oacc1[8];
  #pragma unroll
  for (int j = 0; j < 8; ++j) {
    oacc0[j] = (f32x4){0.f, 0.f, 0.f, 0.f};
    oacc1[j] = (f32x4){0.f, 0.f, 0.f, 0.f};
  }
  float M0 = -3.0e38f, L0v = 0.f, M1 = -3.0e38f, L1v = 0.f;

  stage_g(gN, gbuf0, 0, w, l16, quad);   // prologue

  #pragma unroll 1
  for (int mc = 0; mc < 8; ++mc) {
    const int m0 = mc * 128;
    ushort_t* cbuf = (mc & 1) ? gbuf1 : gbuf0;
    ushort_t* nbuf = (mc & 1) ? gbuf0 : gbuf1;
    // ---- QK^T for both q-groups (phi frags loaded once) ----
    const f32x4 z = (f32x4){0.f, 0.f, 0.f, 0.f};
    f32x4 st0[8], st1[8];
    #pragma unroll
    for (int i = 0; i < 8; ++i) {
      short8 aph = *(const short8*)(phiN + (size_t)(m0 + i * 16 + l16) * 32 + quad * 8);
      st0[i] = __builtin_amdgcn_mfma_f32_16x16x32_bf16(aph, bth0, z, 0, 0, 0);
      st1[i] = __builtin_amdgcn_mfma_f32_16x16x32_bf16(aph, bth1, z, 0, 0, 0);
    }
    // ---- two independent lane-local softmax chains ----
    unsigned int pk0[16], pk1[16];
    softmax_step(st0, M0, L0v, oacc0, pk0);
    softmax_step(st1, M1, L1v, oacc1, pk1);
    __syncthreads();                     // publish cbuf (drains DMA)
    if (mc < 7) stage_g(gN, nbuf, m0 + 128, w, l16, quad);
    // ---- PV: pb direct from registers (phi pi-permutation makes it valid) ----
    __builtin_amdgcn_s_setprio(1);
    #pragma unroll
    for (int s = 0; s < 4; ++s) {
      uint32x4 u0 = {pk0[4 * s], pk0[4 * s + 1], pk0[4 * s + 2], pk0[4 * s + 3]};
      uint32x4 u1 = {pk1[4 * s], pk1[4 * s + 1], pk1[4 * s + 2], pk1[4 * s + 3]};
      short8 pb0 = __builtin_bit_cast(short8, u0);
      short8 pb1 = __builtin_bit_cast(short8, u1);
      #pragma unroll
      for (int j = 0; j < 8; ++j) {
        short8 gf = *(const short8*)(cbuf + (size_t)(j * 4 + s) * 512 + lane * 8);
        oacc0[j] = __builtin_amdgcn_mfma_f32_16x16x32_bf16(gf, pb0, oacc0[j], 0, 0, 0);
        oacc1[j] = __builtin_amdgcn_mfma_f32_16x16x32_bf16(gf, pb1, oacc1[j], 0, 0, 0);
      }
    }
    __builtin_amdgcn_s_setprio(0);
  }
  __syncthreads();   // all PV done; gbuf region becomes outb

  // ---- epilogue: aO direct from accumulator; Wo_fb is pi^-1-permuted ----
  #pragma unroll
  for (int qg = 0; qg < 2; ++qg) {
    f32x4* oa = qg ? oacc1 : oacc0;
    const float invL = 1.f / (qg ? L1v : L0v);
    f32x4 acc2[16];
    #pragma unroll
    for (int i = 0; i < 16; ++i) acc2[i] = (f32x4){0.f, 0.f, 0.f, 0.f};
    #pragma unroll
    for (int kc = 0; kc < 4; ++kc) {
      uint32x4 u;
      u[0] = pack_bf2(oa[2 * kc][0] * invL, oa[2 * kc][1] * invL);
      u[1] = pack_bf2(oa[2 * kc][2] * invL, oa[2 * kc][3] * invL);
      u[2] = pack_bf2(oa[2 * kc + 1][0] * invL, oa[2 * kc + 1][1] * invL);
      u[3] = pack_bf2(oa[2 * kc + 1][2] * invL, oa[2 * kc + 1][3] * invL);
      short8 aO = __builtin_bit_cast(short8, u);
      #pragma unroll
      for (int oct = 0; oct < 16; ++oct) {
        short8 bw = *(const short8*)(Wo_fb + (((size_t)(kc * 16 + oct) * 64 + lane) << 3));
        acc2[oct] = __builtin_amdgcn_mfma_f32_16x16x32_bf16(aO, bw, acc2[oct], 0, 0, 0);
      }
    }
    #pragma unroll
    for (int oct = 0; oct < 16; ++oct) {
      #pragma unroll
      for (int r = 0; r < 4; ++r)
        outb[(oct * 16 + l16) * 132 + w * 32 + qg * 16 + quad * 4 + r] = f2bf(acc2[oct][r]);
    }
  }
  __syncthreads();
  // ---- residual + coalesced stores (128 cols) ----
  {
    const float gm = gamma_p[0];
    const int lid = t & 31;
    const int ocr = t >> 5;
    #pragma unroll 8
    for (int ocg = 0; ocg < 32; ++ocg) {
      int row = ocg * 8 + ocr;
      ushort4v ov = *(const ushort4v*)(&outb[row * 132 + lid * 4]);
      const float* xp = x + ((size_t)n * 256 + row) * 4096 + l0 + lid * 4;
      float* op = out + ((size_t)n * 256 + row) * 4096 + l0 + lid * 4;
      float4 xv = *(const float4*)xp;
      float4 v;
      v.x = xv.x + gm * bf2f(ov[0]);
      v.y = xv.y + gm * bf2f(ov[1]);
      v.z = xv.z + gm * bf2f(ov[2]);
      v.w = xv.w + gm * bf2f(ov[3]);
      *(float4*)op = v;
    }
  }
}

extern "C" void kernel_launch(void* const* d_in, const int* in_sizes, int n_in,
                              void* d_out, int out_size, void* d_ws, size_t ws_size,
                              hipStream_t stream) {
  const float* x  = (const float*)d_in[0];
  const float* Wt = (const float*)d_in[1];
  const float* Wp = (const float*)d_in[2];
  const float* Wg = (const float*)d_in[3];
  const float* Wo = (const float*)d_in[4];
  const float* ut = (const float*)d_in[5];
  const float* up = (const float*)d_in[6];
  const float* ug = (const float*)d_in[7];
  const float* uo = (const float*)d_in[8];
  const float* gamma = (const float*)d_in[9];
  float* ws  = (float*)d_ws;
  float* out = (float*)d_out;

  ushort_t* wb      = (ushort_t*)(ws + WS_WB_F);
  ushort_t* Wo_b    = (ushort_t*)(ws + WS_WO_F);
  ushort_t* theta_b = (ushort_t*)(ws + WS_TH_F);
  ushort_t* phi_b   = (ushort_t*)(ws + WS_PH_F);
  ushort_t* g_b     = (ushort_t*)(ws + WS_G_F);

  sn_kernel<<<4, 256, 0, stream>>>(Wt, Wp, Wg, Wo, ut, up, ug, uo, ws);
  proj_mfma<<<dim3(32, 16), 256, 0, stream>>>(x, wb, theta_b, phi_b, g_b);
  attn_mfma<<<dim3(32, 16), 256, 0, stream>>>(x, theta_b, phi_b, g_b, Wo_b, gamma, out);
}